// Round 7
// baseline (121.992 us; speedup 1.0000x reference)
//
#include <hip/hip_runtime.h>

#define NBINS 8192
#define IMG_HW 36864      // 192*192
#define KA_BLKPI 144      // kA blocks per image (144*256 = IMG_HW)
#define NINST 32
#define NHALF 16          // instances per kB block
#define CCH 16
#define NH 32
#define PADW 28672        // 256*256 - 192*192
#define NB 2
#define EPSF 1e-6f
#define NACC (NINST * (CCH + 1))   // 544: 512 channel sums + 32 counts

typedef unsigned long long u64;
typedef long long i64;

// ------------------------------------------------------------------
// Workspace layout (bytes):
//   wg       : NB*NBINS*8        = 131072  (w in low32, gw in high32)
//   partials : NB*144*544*8      = 1253376 (i64 fixed-point x 2^32)
//   centers  : NB*32*16*4        = 4096
//   q        : NB*32*32*4        = 8192
//   meta     : 8*4               [errlo, scale, maxa0, maxa1, G0, G1]
//   ticket   : 4
// ------------------------------------------------------------------
#define OFF_WG   0
#define OFF_PART 131072
#define OFF_CENT 1384448
#define OFF_Q    1388544
#define OFF_META 1396736
#define OFF_TKT  1396768

// kA: per-block center partial sums (i64 fixed-point => order-invariant,
// bit-deterministic). Also zeroes wg and ticket.
__global__ void __launch_bounds__(256)
k_centers(const float* __restrict__ emb, const int* __restrict__ gt,
          i64* __restrict__ partials, u64* __restrict__ wg,
          unsigned int* __restrict__ ticket) {
    int blk = blockIdx.x, b = blockIdx.y;
    int tid = threadIdx.x;
    __shared__ i64 acc[NACC];
    for (int i = tid; i < NACC; i += 256) acc[i] = 0;
    int gid = (b * KA_BLKPI + blk) * 256 + tid;
    if (gid < NB * NBINS) wg[gid] = 0ull;
    if (gid == 0) *ticket = 0u;
    __syncthreads();

    int pix = blk * 256 + tid;
    int gtv = gt[(size_t)b * IMG_HW + pix];
    if (gtv > 0) {
        int n = gtv - 1;
        const float* e = emb + (size_t)b * CCH * IMG_HW + pix;
#pragma unroll
        for (int c = 0; c < CCH; c++) {
            i64 fx = (i64)((double)e[c * IMG_HW] * 4294967296.0);
            atomicAdd((u64*)&acc[n * CCH + c], (u64)fx);
        }
        atomicAdd((u64*)&acc[NINST * CCH + n], 1ull);
    }
    __syncthreads();
    i64* pb = partials + ((size_t)b * KA_BLKPI + blk) * NACC;
    for (int i = tid; i < NACC; i += 256) pb[i] = acc[i];
}

// kF: one block per image. Reduce partials ONCE; write centers/q/meta to
// global; insert the (collapsed) padded-region items.
__global__ void __launch_bounds__(256)
k_finalize(const float* __restrict__ W1, const float* __restrict__ b1,
           const float* __restrict__ W2, const float* __restrict__ b2,
           const i64* __restrict__ partials,
           float* __restrict__ centers, float* __restrict__ qout,
           float* __restrict__ meta, u64* __restrict__ wg) {
    int b = blockIdx.x;
    int tid = threadIdx.x;
    __shared__ i64 sum_s[NACC];
    __shared__ float a_s[NINST][CCH];
    __shared__ float redf[4];
    __shared__ float sconst[2];

    for (int i = tid; i < NACC; i += 256) {
        i64 s = 0;
        const i64* pp = partials + (size_t)b * KA_BLKPI * NACC + i;
#pragma unroll 8
        for (int p = 0; p < KA_BLKPI; p++) s += pp[(size_t)p * NACC];
        sum_s[i] = s;
    }
    __syncthreads();

    for (int i = tid; i < NINST * CCH; i += 256) {
        int n = i / CCH, c = i % CCH;
        float cntf = (float)sum_s[NINST * CCH + n] + EPSF;
        float a = (float)((double)sum_s[i] * (1.0 / 4294967296.0)) / cntf * (1.f / 32.f);
        a_s[n][c] = a;
        centers[((size_t)b * NINST + n) * CCH + c] = a;
    }
    __syncthreads();
    for (int i = tid; i < NINST * NH; i += 256) {
        int n = i / NH, j = i % NH;
        float s = b1[j];
#pragma unroll
        for (int c = 0; c < CCH; c++) s += a_s[n][c] * W1[c * NH + j];
        qout[((size_t)b * NINST + n) * NH + j] = s;
    }
    float ma = 0.f;
    for (int i = tid; i < NINST * CCH; i += 256) ma = fmaxf(ma, fabsf(a_s[i / CCH][i % CCH]));
#pragma unroll
    for (int off = 32; off > 0; off >>= 1) ma = fmaxf(ma, __shfl_down(ma, off, 64));
    if ((tid & 63) == 0) redf[tid >> 6] = ma;
    __syncthreads();
    if (tid == 0) {
        float m = fmaxf(fmaxf(redf[0], redf[1]), fmaxf(redf[2], redf[3]));
        meta[2 + b] = m;
        float Gs = 0.f;
        for (int n = 0; n < NINST; n++) Gs += (float)sum_s[NINST * CCH + n];
        meta[4 + b] = Gs;
        // conservative bound L on |logit|
        float L = fabsf(b2[0]);
        for (int j = 0; j < NH; j++) {
            float sa = 0.f;
            for (int c = 0; c < CCH; c++) sa += fabsf(W1[c * NH + j]);
            L += fmaxf(b1[j] + 2.f * sa, 0.f) * fabsf(W2[j]);
        }
        L += 1.f;  // margin
        float errlo = 1.f - L;
        float scale = (float)NBINS / (2.f * L);
        meta[0] = errlo;
        meta[1] = scale;
        sconst[0] = errlo;
        sconst[1] = scale;
    }
    __syncthreads();
    // padded-region items: emb=0, label=0, weight PADW per instance.
    if (tid < NINST) {
        int n = tid;
        float logit = b2[0];
        for (int j = 0; j < NH; j++) {
            float s = b1[j];
#pragma unroll
            for (int c = 0; c < CCH; c++)
                s += fminf(fmaxf(a_s[n][c], -2.f), 2.f) * W1[c * NH + j];
            logit += fmaxf(s, 0.f) * W2[j];
        }
        float er = 1.f + logit;
        int bin = min(max((int)((er - sconst[0]) * sconst[1]), 0), NBINS - 1);
        atomicAdd(&wg[(size_t)b * NBINS + bin], (u64)PADW);
    }
}

// kB: 576 blocks: (pixblock, half-of-instances, image). 256 pixels x 16
// instances per block -> 2.25 blocks/CU for latency hiding, half the
// LDS-atomic pressure per block. Last-block ticket does the Jaccard scan.
__global__ void __launch_bounds__(256, 3)
k_hist(const float* __restrict__ emb, const int* __restrict__ gt,
       const float* __restrict__ W1, const float* __restrict__ b1,
       const float* __restrict__ W2, const float* __restrict__ b2,
       const float* __restrict__ centers, const float* __restrict__ q,
       const float* __restrict__ meta,
       u64* __restrict__ wg, unsigned int* __restrict__ ticket,
       float* __restrict__ out) {
    __shared__ unsigned int hist[NBINS];      // 32 KB
    __shared__ float q_s[NHALF][NH];
    __shared__ float a_s[NHALF][CCH];
    __shared__ float W2s[NH], b1s[NH];
    __shared__ float cons[4];

    int bx = blockIdx.x;
    int pixblk = bx >> 1, half = bx & 1;
    int b = blockIdx.y;
    int tid = threadIdx.x;
    int n0 = half * NHALF;

    // issue pixel loads first (overlap their latency with LDS staging)
    int pix = pixblk * 256 + tid;
    int gtv = gt[(size_t)b * IMG_HW + pix];
    const float* e = emb + (size_t)b * CCH * IMG_HW + pix;
    float u[CCH];
#pragma unroll
    for (int c = 0; c < CCH; c++) u[c] = e[c * IMG_HW];

    for (int i = tid; i < NBINS; i += 256) hist[i] = 0u;
    for (int i = tid; i < NHALF * NH; i += 256)
        q_s[i / NH][i % NH] = q[((size_t)b * NINST + n0) * NH + i];
    for (int i = tid; i < NHALF * CCH; i += 256)
        a_s[i / CCH][i % CCH] = centers[((size_t)b * NINST + n0) * CCH + i];
    if (tid < NH) { W2s[tid] = W2[tid]; b1s[tid] = b1[tid]; }
    if (tid == 0) { cons[0] = b2[0]; cons[1] = meta[0]; cons[2] = meta[1]; cons[3] = meta[2 + b]; }
    __syncthreads();

    float maxu = 0.f;
#pragma unroll
    for (int c = 0; c < CCH; c++) {
        u[c] *= (1.f / 32.f);
        maxu = fmaxf(maxu, fabsf(u[c]));
    }
    float b2v = cons[0], errlo = cons[1], scale = cons[2], maxa = cons[3];

    if (maxu + maxa <= 2.f) {
        // no element can clip: h = relu(q_n - v), v shared across instances
        float v[NH];
#pragma unroll
        for (int j = 0; j < NH; j++) {
            float s = 0.f;
#pragma unroll
            for (int c = 0; c < CCH; c++) s += u[c] * W1[c * NH + j];
            v[j] = s;
        }
        for (int n = 0; n < NHALF; n++) {
            float logit = b2v;
#pragma unroll
            for (int j = 0; j < NH; j++)
                logit += fmaxf(q_s[n][j] - v[j], 0.f) * W2s[j];
            unsigned int label = (gtv == n0 + n + 1) ? 1u : 0u;
            float er = label ? (1.f - logit) : (1.f + logit);
            int bin = min(max((int)((er - errlo) * scale), 0), NBINS - 1);
            atomicAdd(&hist[bin], 1u | (label << 16));
        }
    } else {
        // exact slow path with per-element clip
        for (int n = 0; n < NHALF; n++) {
            float logit = b2v;
            for (int j = 0; j < NH; j++) {
                float s = b1s[j];
#pragma unroll
                for (int c = 0; c < CCH; c++) {
                    float f = fminf(fmaxf(a_s[n][c] - u[c], -2.f), 2.f);
                    s += f * W1[c * NH + j];
                }
                logit += fmaxf(s, 0.f) * W2s[j];
            }
            unsigned int label = (gtv == n0 + n + 1) ? 1u : 0u;
            float er = label ? (1.f - logit) : (1.f + logit);
            int bin = min(max((int)((er - errlo) * scale), 0), NBINS - 1);
            atomicAdd(&hist[bin], 1u | (label << 16));
        }
    }
    __syncthreads();
    {
        u64* wgb = wg + (size_t)b * NBINS;
        for (int i = tid; i < NBINS; i += 256) {
            unsigned int h = hist[i];
            if (h) atomicAdd(&wgb[i], (u64)(h & 0xffffu) | ((u64)(h >> 16) << 32));
        }
    }

    // ---- last-block ticket (losers exit) ----
    __threadfence();
    __syncthreads();
    __shared__ unsigned int stk;
    if (tid == 0)
        stk = __hip_atomic_fetch_add(ticket, 1u, __ATOMIC_ACQ_REL,
                                     __HIP_MEMORY_SCOPE_AGENT);
    __syncthreads();
    if (stk != (unsigned)(NB * 2 * KA_BLKPI * 2 / 2 - 1)) return;  // 576-1

    // ---- winner: descending-bin Jaccard scan over both images ----
    __shared__ u64 wpart[4];
    __shared__ double dred[4];
    const int BPT = NBINS / 256;   // 32 bins per thread
    double total = 0.0;
    int lane = tid & 63, wid = tid >> 6;
    double delo = (double)errlo;
    double invscale = 1.0 / (double)scale;
    for (int bb = 0; bb < NB; bb++) {
        const u64* wgs = wg + (size_t)bb * NBINS;
        double G = (double)meta[4 + bb];

        u64 tot = 0;
        for (int k = 0; k < BPT; k++) {
            int bin = NBINS - 1 - (tid * BPT + k);
            tot += __hip_atomic_load(&wgs[bin], __ATOMIC_RELAXED,
                                     __HIP_MEMORY_SCOPE_AGENT);
        }
        u64 incl = tot;
#pragma unroll
        for (int off = 1; off < 64; off <<= 1) {
            u64 x = __shfl_up(incl, off, 64);
            if (lane >= off) incl += x;
        }
        if (lane == 63) wpart[wid] = incl;
        __syncthreads();
        u64 woff = 0;
        for (int w = 0; w < wid; w++) woff += wpart[w];
        u64 excl = woff + incl - tot;
        unsigned int p = (unsigned int)(excl & 0xffffffffull);
        unsigned int cs = (unsigned int)(excl >> 32);

        double loss = 0.0;
        if (G > 0.5) {
            for (int k = 0; k < BPT; k++) {
                int bin = NBINS - 1 - (tid * BPT + k);
                u64 v = __hip_atomic_load(&wgs[bin], __ATOMIC_RELAXED,
                                          __HIP_MEMORY_SCOPE_AGENT);
                unsigned int w = (unsigned int)(v & 0xffffffffull);
                unsigned int g = (unsigned int)(v >> 32);
                if (w) {
                    double Js = 1.0 - (G - (double)cs) / (G + (double)p - (double)cs);
                    unsigned int pe = p + w, ce = cs + g;
                    double Je = 1.0 - (G - (double)ce) / (G + (double)pe - (double)ce);
                    double rep = delo + ((double)bin + 0.5) * invscale;
                    if (rep < 0.0) rep = 0.0;
                    loss += rep * (Je - Js);
                    p = pe;
                    cs = ce;
                }
            }
        }
#pragma unroll
        for (int off = 32; off > 0; off >>= 1) loss += __shfl_down(loss, off, 64);
        if (lane == 0) dred[wid] = loss;
        __syncthreads();
        if (tid == 0) total += dred[0] + dred[1] + dred[2] + dred[3];
        __syncthreads();
    }
    if (tid == 0) out[0] = (float)(total * 0.5);  // mean over 2 images
}

extern "C" void kernel_launch(void* const* d_in, const int* in_sizes, int n_in,
                              void* d_out, int out_size, void* d_ws, size_t ws_size,
                              hipStream_t stream) {
    const float* emb = (const float*)d_in[0];
    const int* gt = (const int*)d_in[1];
    const float* W1 = (const float*)d_in[2];
    const float* b1 = (const float*)d_in[3];
    const float* W2 = (const float*)d_in[4];
    const float* b2 = (const float*)d_in[5];
    float* out = (float*)d_out;
    char* ws = (char*)d_ws;

    u64* wg = (u64*)(ws + OFF_WG);
    i64* partials = (i64*)(ws + OFF_PART);
    float* centers = (float*)(ws + OFF_CENT);
    float* q = (float*)(ws + OFF_Q);
    float* meta = (float*)(ws + OFF_META);
    unsigned int* ticket = (unsigned int*)(ws + OFF_TKT);

    k_centers<<<dim3(KA_BLKPI, NB), 256, 0, stream>>>(emb, gt, partials, wg, ticket);
    k_finalize<<<dim3(NB), 256, 0, stream>>>(W1, b1, W2, b2, partials, centers, q, meta, wg);
    k_hist<<<dim3(2 * KA_BLKPI, NB), 256, 0, stream>>>(emb, gt, W1, b1, W2, b2,
                                                       centers, q, meta, wg, ticket, out);
}

// Round 8
// 109.313 us; speedup vs baseline: 1.1160x; 1.1160x over previous
//
#include <hip/hip_runtime.h>

#define NBINS 8192
#define IMG_HW 36864      // 192*192
#define KA_BLKPI 144      // blocks per image (144*256 = IMG_HW)
#define NINST 32
#define CCH 16
#define NH 32
#define PADW 28672        // 256*256 - 192*192
#define NB 2
#define EPSF 1e-6f
#define NACC (NINST * (CCH + 1))   // 544: 512 channel sums + 32 counts

typedef unsigned long long u64;
typedef long long i64;

// ------------------------------------------------------------------
// Workspace layout (bytes):
//   wg       : NB*NBINS*8   =  131072  (w in low32, gw in high32)
//   partials : NB*144*544*8 = 1253376  (i64 fixed-point x 2^32)
//   maxblk   : NB*144*4     =    1152  (per-block max|emb|)
//   centers  : NB*32*16*4   =    4096
//   q        : NB*32*32*4   =    8192
//   meta     : 8*4          [scale0, scale1, maxa0, maxa1, G0, G1]
//   ticket   : 4
// ------------------------------------------------------------------
#define OFF_WG   0
#define OFF_PART 131072
#define OFF_MAXB 1384448
#define OFF_CENT 1385600
#define OFF_Q    1389696
#define OFF_META 1397888
#define OFF_TKT  1397920

// kA: center partial sums (i64 fixed-point => order-invariant) + per-block
// max|emb|. Also zeroes wg and ticket.
__global__ void __launch_bounds__(256)
k_centers(const float* __restrict__ emb, const int* __restrict__ gt,
          i64* __restrict__ partials, float* __restrict__ maxblk,
          u64* __restrict__ wg, unsigned int* __restrict__ ticket) {
    int blk = blockIdx.x, b = blockIdx.y;
    int tid = threadIdx.x;
    __shared__ i64 acc[NACC];
    __shared__ float mred[4];
    for (int i = tid; i < NACC; i += 256) acc[i] = 0;
    int gid = (b * KA_BLKPI + blk) * 256 + tid;
    if (gid < NB * NBINS) wg[gid] = 0ull;
    if (gid == 0) *ticket = 0u;
    __syncthreads();

    int pix = blk * 256 + tid;
    int gtv = gt[(size_t)b * IMG_HW + pix];
    const float* e = emb + (size_t)b * CCH * IMG_HW + pix;
    float ev[CCH];
    float me = 0.f;
#pragma unroll
    for (int c = 0; c < CCH; c++) {
        ev[c] = e[c * IMG_HW];
        me = fmaxf(me, fabsf(ev[c]));
    }
    if (gtv > 0) {
        int n = gtv - 1;
#pragma unroll
        for (int c = 0; c < CCH; c++) {
            i64 fx = (i64)((double)ev[c] * 4294967296.0);
            atomicAdd((u64*)&acc[n * CCH + c], (u64)fx);
        }
        atomicAdd((u64*)&acc[NINST * CCH + n], 1ull);
    }
#pragma unroll
    for (int off = 32; off > 0; off >>= 1) me = fmaxf(me, __shfl_down(me, off, 64));
    if ((tid & 63) == 0) mred[tid >> 6] = me;
    __syncthreads();
    if (tid == 0)
        maxblk[b * KA_BLKPI + blk] = fmaxf(fmaxf(mred[0], mred[1]), fmaxf(mred[2], mred[3]));
    i64* pb = partials + ((size_t)b * KA_BLKPI + blk) * NACC;
    for (int i = tid; i < NACC; i += 256) pb[i] = acc[i];
}

// kF: one block per image. Reduce partials + maxblk; centers/q to global;
// tight per-image error range via exact per-(n,j) interval arithmetic;
// insert padded-region items.
__global__ void __launch_bounds__(256)
k_finalize(const float* __restrict__ W1, const float* __restrict__ b1,
           const float* __restrict__ W2, const float* __restrict__ b2,
           const i64* __restrict__ partials, const float* __restrict__ maxblk,
           float* __restrict__ centers, float* __restrict__ qout,
           float* __restrict__ meta, u64* __restrict__ wg) {
    int b = blockIdx.x;
    int tid = threadIdx.x;
    __shared__ i64 sum_s[NACC];
    __shared__ float a_s[NINST][CCH];
    __shared__ float hminw[NINST][NH];
    __shared__ float hmaxw[NINST][NH];
    __shared__ float redf[4];
    __shared__ float semax[NINST];
    __shared__ float sconst[2];

    for (int i = tid; i < NACC; i += 256) {
        i64 s = 0;
        const i64* pp = partials + (size_t)b * KA_BLKPI * NACC + i;
#pragma unroll 8
        for (int p = 0; p < KA_BLKPI; p++) s += pp[(size_t)p * NACC];
        sum_s[i] = s;
    }
    // global max|emb| -> maxu
    float me = (tid < KA_BLKPI) ? maxblk[b * KA_BLKPI + tid] : 0.f;
#pragma unroll
    for (int off = 32; off > 0; off >>= 1) me = fmaxf(me, __shfl_down(me, off, 64));
    if ((tid & 63) == 0) redf[tid >> 6] = me;
    __syncthreads();
    float maxu = fmaxf(fmaxf(redf[0], redf[1]), fmaxf(redf[2], redf[3])) * (1.f / 32.f);

    for (int i = tid; i < NINST * CCH; i += 256) {
        int n = i / CCH, c = i % CCH;
        float cntf = (float)sum_s[NINST * CCH + n] + EPSF;
        float a = (float)((double)sum_s[i] * (1.0 / 4294967296.0)) / cntf * (1.f / 32.f);
        a_s[n][c] = a;
        centers[((size_t)b * NINST + n) * CCH + c] = a;
    }
    __syncthreads();
    // q = a@W1+b1 AND per-(n,j) h-range contributions (f_c in [lo,hi], exact)
    for (int i = tid; i < NINST * NH; i += 256) {
        int n = i / NH, j = i % NH;
        float s = b1[j], smin = b1[j], smax = b1[j];
#pragma unroll
        for (int c = 0; c < CCH; c++) {
            float w = W1[c * NH + j];
            float a = a_s[n][c];
            float lo = fmaxf(a - maxu, -2.f);
            float hi = fminf(a + maxu, 2.f);
            s += a * w;
            if (w >= 0.f) { smin += lo * w; smax += hi * w; }
            else          { smin += hi * w; smax += lo * w; }
        }
        qout[((size_t)b * NINST + n) * NH + j] = s;
        float hlo = fmaxf(smin, 0.f), hhi = fmaxf(smax, 0.f);
        float w2 = W2[j];
        if (w2 >= 0.f) { hminw[n][j] = hlo * w2; hmaxw[n][j] = hhi * w2; }
        else           { hminw[n][j] = hhi * w2; hmaxw[n][j] = hlo * w2; }
    }
    float ma = 0.f;
    for (int i = tid; i < NINST * CCH; i += 256) ma = fmaxf(ma, fabsf(a_s[i / CCH][i % CCH]));
#pragma unroll
    for (int off = 32; off > 0; off >>= 1) ma = fmaxf(ma, __shfl_down(ma, off, 64));
    if ((tid & 63) == 0) redf[tid >> 6] = ma;
    __syncthreads();
    // per-instance logit range -> max possible error
    if (tid < NINST) {
        float lo = b2[0], hi = b2[0];
        for (int j = 0; j < NH; j++) { lo += hminw[tid][j]; hi += hmaxw[tid][j]; }
        semax[tid] = 1.f + fmaxf(hi, -lo);
    }
    __syncthreads();
    if (tid == 0) {
        float m = fmaxf(fmaxf(redf[0], redf[1]), fmaxf(redf[2], redf[3]));
        meta[2 + b] = m;
        float Gs = 0.f;
        for (int n = 0; n < NINST; n++) Gs += (float)sum_s[NINST * CCH + n];
        meta[4 + b] = Gs;
        float errhi = 0.f;
        for (int n = 0; n < NINST; n++) errhi = fmaxf(errhi, semax[n]);
        errhi += 1e-3f;  // margin
        float scale = (float)NBINS / errhi;
        meta[b] = scale;
        sconst[0] = scale;
    }
    __syncthreads();
    // padded-region items: emb=0, label=0, weight PADW per instance (e>0 only)
    if (tid < NINST) {
        int n = tid;
        float logit = b2[0];
        for (int j = 0; j < NH; j++) {
            float s = b1[j];
#pragma unroll
            for (int c = 0; c < CCH; c++)
                s += fminf(fmaxf(a_s[n][c], -2.f), 2.f) * W1[c * NH + j];
            logit += fmaxf(s, 0.f) * W2[j];
        }
        float er = 1.f + logit;
        if (er > 0.f) {
            int bin = min((int)(er * sconst[0]), NBINS - 1);
            atomicAdd(&wg[(size_t)b * NBINS + bin], (u64)PADW);
        }
    }
}

// kB: 288 blocks, 256 pixels x 32 instances each; LDS hist (8192 bins over
// the TIGHT (0, errhi] range -> near-zero same-bin wave conflicts); items
// with e<=0 dropped (exact: relu=0 and they never prefix kept items).
// Last-block ticket runs the descending-bin Jaccard scan.
__global__ void __launch_bounds__(256, 4)
k_hist(const float* __restrict__ emb, const int* __restrict__ gt,
       const float* __restrict__ W1, const float* __restrict__ b1,
       const float* __restrict__ W2, const float* __restrict__ b2,
       const float* __restrict__ centers, const float* __restrict__ q,
       const float* __restrict__ meta,
       u64* __restrict__ wg, unsigned int* __restrict__ ticket,
       float* __restrict__ out) {
    __shared__ unsigned int hist[NBINS];      // 32 KB
    __shared__ float q_s[NINST][NH];
    __shared__ float a_s[NINST][CCH];
    __shared__ float W2s[NH], b1s[NH];
    __shared__ float cons[4];

    int pixblk = blockIdx.x, b = blockIdx.y;
    int tid = threadIdx.x;

    // issue pixel loads first (overlap latency with LDS staging)
    int pix = pixblk * 256 + tid;
    int gtv = gt[(size_t)b * IMG_HW + pix];
    const float* e = emb + (size_t)b * CCH * IMG_HW + pix;
    float u[CCH];
#pragma unroll
    for (int c = 0; c < CCH; c++) u[c] = e[c * IMG_HW];

    for (int i = tid; i < NBINS; i += 256) hist[i] = 0u;
    for (int i = tid; i < NINST * NH; i += 256) q_s[i / NH][i % NH] = q[(size_t)b * NINST * NH + i];
    for (int i = tid; i < NINST * CCH; i += 256) a_s[i / CCH][i % CCH] = centers[(size_t)b * NINST * CCH + i];
    if (tid < NH) { W2s[tid] = W2[tid]; b1s[tid] = b1[tid]; }
    if (tid == 0) { cons[0] = b2[0]; cons[1] = meta[b]; cons[2] = meta[2 + b]; }
    __syncthreads();

    float maxu = 0.f;
#pragma unroll
    for (int c = 0; c < CCH; c++) {
        u[c] *= (1.f / 32.f);
        maxu = fmaxf(maxu, fabsf(u[c]));
    }
    float b2v = cons[0], scale = cons[1], maxa = cons[2];

    if (maxu + maxa <= 2.f) {
        // no element can clip: h = relu(q_n - v), v shared across instances
        float v[NH];
#pragma unroll
        for (int j = 0; j < NH; j++) {
            float s = 0.f;
#pragma unroll
            for (int c = 0; c < CCH; c++) s += u[c] * W1[c * NH + j];
            v[j] = s;
        }
        for (int n = 0; n < NINST; n++) {
            float logit = b2v;
#pragma unroll
            for (int j = 0; j < NH; j++)
                logit += fmaxf(q_s[n][j] - v[j], 0.f) * W2s[j];
            unsigned int label = (gtv == n + 1) ? 1u : 0u;
            float er = label ? (1.f - logit) : (1.f + logit);
            if (er > 0.f) {
                int bin = min((int)(er * scale), NBINS - 1);
                atomicAdd(&hist[bin], 1u | (label << 16));
            }
        }
    } else {
        // exact slow path with per-element clip
        for (int n = 0; n < NINST; n++) {
            float logit = b2v;
            for (int j = 0; j < NH; j++) {
                float s = b1s[j];
#pragma unroll
                for (int c = 0; c < CCH; c++) {
                    float f = fminf(fmaxf(a_s[n][c] - u[c], -2.f), 2.f);
                    s += f * W1[c * NH + j];
                }
                logit += fmaxf(s, 0.f) * W2s[j];
            }
            unsigned int label = (gtv == n + 1) ? 1u : 0u;
            float er = label ? (1.f - logit) : (1.f + logit);
            if (er > 0.f) {
                int bin = min((int)(er * scale), NBINS - 1);
                atomicAdd(&hist[bin], 1u | (label << 16));
            }
        }
    }
    __syncthreads();
    {
        u64* wgb = wg + (size_t)b * NBINS;
        for (int i = tid; i < NBINS; i += 256) {
            unsigned int h = hist[i];
            if (h) atomicAdd(&wgb[i], (u64)(h & 0xffffu) | ((u64)(h >> 16) << 32));
        }
    }

    // ---- last-block ticket (losers exit) ----
    __threadfence();
    __syncthreads();
    __shared__ unsigned int stk;
    if (tid == 0)
        stk = __hip_atomic_fetch_add(ticket, 1u, __ATOMIC_ACQ_REL,
                                     __HIP_MEMORY_SCOPE_AGENT);
    __syncthreads();
    if (stk != (unsigned)(NB * KA_BLKPI - 1)) return;

    // ---- winner: descending-bin Jaccard scan over both images ----
    __shared__ u64 wpart[4];
    __shared__ double dred[4];
    const int BPT = NBINS / 256;   // 32 bins per thread
    double total = 0.0;
    int lane = tid & 63, wid = tid >> 6;
    for (int bb = 0; bb < NB; bb++) {
        const u64* wgs = wg + (size_t)bb * NBINS;
        double G = (double)meta[4 + bb];
        double invscale = 1.0 / (double)meta[bb];

        u64 tot = 0;
        for (int k = 0; k < BPT; k++) {
            int bin = NBINS - 1 - (tid * BPT + k);
            tot += __hip_atomic_load(&wgs[bin], __ATOMIC_RELAXED,
                                     __HIP_MEMORY_SCOPE_AGENT);
        }
        u64 incl = tot;
#pragma unroll
        for (int off = 1; off < 64; off <<= 1) {
            u64 x = __shfl_up(incl, off, 64);
            if (lane >= off) incl += x;
        }
        if (lane == 63) wpart[wid] = incl;
        __syncthreads();
        u64 woff = 0;
        for (int w = 0; w < wid; w++) woff += wpart[w];
        u64 excl = woff + incl - tot;
        unsigned int p = (unsigned int)(excl & 0xffffffffull);
        unsigned int cs = (unsigned int)(excl >> 32);

        double loss = 0.0;
        if (G > 0.5) {
            for (int k = 0; k < BPT; k++) {
                int bin = NBINS - 1 - (tid * BPT + k);
                u64 v = __hip_atomic_load(&wgs[bin], __ATOMIC_RELAXED,
                                          __HIP_MEMORY_SCOPE_AGENT);
                unsigned int w = (unsigned int)(v & 0xffffffffull);
                unsigned int g = (unsigned int)(v >> 32);
                if (w) {
                    double Js = 1.0 - (G - (double)cs) / (G + (double)p - (double)cs);
                    unsigned int pe = p + w, ce = cs + g;
                    double Je = 1.0 - (G - (double)ce) / (G + (double)pe - (double)ce);
                    double rep = ((double)bin + 0.5) * invscale;
                    loss += rep * (Je - Js);
                    p = pe;
                    cs = ce;
                }
            }
        }
#pragma unroll
        for (int off = 32; off > 0; off >>= 1) loss += __shfl_down(loss, off, 64);
        if (lane == 0) dred[wid] = loss;
        __syncthreads();
        if (tid == 0) total += dred[0] + dred[1] + dred[2] + dred[3];
        __syncthreads();
    }
    if (tid == 0) out[0] = (float)(total * 0.5);  // mean over 2 images
}

extern "C" void kernel_launch(void* const* d_in, const int* in_sizes, int n_in,
                              void* d_out, int out_size, void* d_ws, size_t ws_size,
                              hipStream_t stream) {
    const float* emb = (const float*)d_in[0];
    const int* gt = (const int*)d_in[1];
    const float* W1 = (const float*)d_in[2];
    const float* b1 = (const float*)d_in[3];
    const float* W2 = (const float*)d_in[4];
    const float* b2 = (const float*)d_in[5];
    float* out = (float*)d_out;
    char* ws = (char*)d_ws;

    u64* wg = (u64*)(ws + OFF_WG);
    i64* partials = (i64*)(ws + OFF_PART);
    float* maxblk = (float*)(ws + OFF_MAXB);
    float* centers = (float*)(ws + OFF_CENT);
    float* q = (float*)(ws + OFF_Q);
    float* meta = (float*)(ws + OFF_META);
    unsigned int* ticket = (unsigned int*)(ws + OFF_TKT);

    k_centers<<<dim3(KA_BLKPI, NB), 256, 0, stream>>>(emb, gt, partials, maxblk, wg, ticket);
    k_finalize<<<dim3(NB), 256, 0, stream>>>(W1, b1, W2, b2, partials, maxblk,
                                             centers, q, meta, wg);
    k_hist<<<dim3(KA_BLKPI, NB), 256, 0, stream>>>(emb, gt, W1, b1, W2, b2,
                                                   centers, q, meta, wg, ticket, out);
}